// Round 1
// 1429.994 us; speedup vs baseline: 1.1921x; 1.1921x over previous
//
#include <hip/hip_runtime.h>
#include <hip/hip_fp16.h>

#define NN 100000
#define NE 1600000
#define DIM 128
#define NGRAPH 128
#define FCD 64

typedef _Float16 half_t;
typedef _Float16 half2_t __attribute__((ext_vector_type(2)));
typedef _Float16 half4_t __attribute__((ext_vector_type(4)));

// ---------------- CSR build ----------------
__global__ void k_count(const int* __restrict__ col, int* __restrict__ deg) {
  int i = blockIdx.x * 256 + threadIdx.x;
  if (i < NE) atomicAdd(&deg[col[i]], 1);
}

__global__ void k_dinv(const int* __restrict__ deg, float* __restrict__ dinv) {
  int i = blockIdx.x * 256 + threadIdx.x;
  if (i < NN) dinv[i] = rsqrtf((float)(deg[i] + 1));  // +1 self loop
}

// 1024 elems/block, 256 thr x int4. Writes block-local exclusive scan + block sums.
__global__ void k_scan1(const int* __restrict__ deg, int* __restrict__ rowptr,
                        int* __restrict__ part) {
  int b = blockIdx.x, t = threadIdx.x;
  int base = b * 1024 + t * 4;
  int4 v = make_int4(0, 0, 0, 0);
  if (base + 4 <= NN) v = *(const int4*)&deg[base];
  else {
    if (base + 0 < NN) v.x = deg[base + 0];
    if (base + 1 < NN) v.y = deg[base + 1];
    if (base + 2 < NN) v.z = deg[base + 2];
    if (base + 3 < NN) v.w = deg[base + 3];
  }
  int s = v.x + v.y + v.z + v.w;
  int lane = t & 63, w = t >> 6;
  int incl = s;
  for (int o = 1; o < 64; o <<= 1) {
    int u = __shfl_up(incl, o);
    if (lane >= o) incl += u;
  }
  __shared__ int wsum[4];
  if (lane == 63) wsum[w] = incl;
  __syncthreads();
  int woff = 0;
  for (int i = 0; i < w; i++) woff += wsum[i];
  int excl = woff + incl - s;
  int r = excl;
  if (base + 0 < NN) { rowptr[base + 0] = r; r += v.x; }
  if (base + 1 < NN) { rowptr[base + 1] = r; r += v.y; }
  if (base + 2 < NN) { rowptr[base + 2] = r; r += v.z; }
  if (base + 3 < NN) { rowptr[base + 3] = r; r += v.w; }
  if (t == 255) part[b] = woff + incl;
}

__global__ void k_scan2(int* __restrict__ part, int* __restrict__ rowptr, int NB) {
  int t = threadIdx.x;  // 128
  int v = (t < NB) ? part[t] : 0;
  int incl = v;
  int lane = t & 63;
  for (int o = 1; o < 64; o <<= 1) {
    int u = __shfl_up(incl, o);
    if (lane >= o) incl += u;
  }
  __shared__ int w0;
  if (t == 63) w0 = incl;
  __syncthreads();
  if (t >= 64) incl += w0;
  if (t < NB) part[t] = incl - v;  // exclusive
  if (t == 0) rowptr[NN] = NE;
}

__global__ void k_scan3(int* __restrict__ rowptr, const int* __restrict__ part) {
  int i = blockIdx.x * 256 + threadIdx.x;
  if (i < NN) rowptr[i] += part[i >> 10];
}

__global__ void k_fill(const int* __restrict__ row, const int* __restrict__ col,
                       const int* __restrict__ rowptr,
                       int* __restrict__ fill, int* __restrict__ csrc) {
  int e = blockIdx.x * 256 + threadIdx.x;
  if (e >= NE) return;
  int r = row[e], c = col[e];
  int pos = rowptr[c] + atomicAdd(&fill[c], 1);
  csrc[pos] = r;
}

// ---------------- GEMM: O[n][j] = dinv[n] * sum_k X[n][k] * W[k][j], fp16 out ----
// 64x64 tile, 4x4 micro-tile/thread, K staged in two halves of 64.
__global__ __launch_bounds__(256) void k_gemm(const float* __restrict__ X,
                                              const float* __restrict__ W,
                                              const float* __restrict__ dinv,
                                              half_t* __restrict__ O) {
  __shared__ float Xs[64 * 68];  // [k][n], stride 68
  __shared__ float Ws[64 * 64];  // [k][j]
  int bid = blockIdx.x;
  int n0 = (bid >> 1) * 64;
  int jb = (bid & 1) * 64;
  int t = threadIdx.x;
  int tx = t & 15, ty = t >> 4;
  float acc[4][4] = {};
  for (int kb = 0; kb < 128; kb += 64) {
    __syncthreads();
    #pragma unroll
    for (int i = 0; i < 4; i++) {
      int e = t + i * 256;       // 0..1023
      int r = e >> 4;            // node row 0..63
      int kq = (e & 15) * 4;     // k quad
      int n = n0 + r;
      float4 v = make_float4(0.f, 0.f, 0.f, 0.f);
      if (n < NN) v = *(const float4*)&X[n * DIM + kb + kq];
      Xs[(kq + 0) * 68 + r] = v.x;
      Xs[(kq + 1) * 68 + r] = v.y;
      Xs[(kq + 2) * 68 + r] = v.z;
      Xs[(kq + 3) * 68 + r] = v.w;
    }
    #pragma unroll
    for (int i = 0; i < 4; i++) {
      int e = t + i * 256;
      int r = e >> 4;            // k row 0..63
      int jq = (e & 15) * 4;
      *(float4*)&Ws[r * 64 + jq] = *(const float4*)&W[(kb + r) * DIM + jb + jq];
    }
    __syncthreads();
    #pragma unroll 8
    for (int k = 0; k < 64; k++) {
      float4 a = *(const float4*)&Xs[k * 68 + ty * 4];
      float4 b = *(const float4*)&Ws[k * 64 + tx * 4];
      acc[0][0] += a.x * b.x; acc[0][1] += a.x * b.y; acc[0][2] += a.x * b.z; acc[0][3] += a.x * b.w;
      acc[1][0] += a.y * b.x; acc[1][1] += a.y * b.y; acc[1][2] += a.y * b.z; acc[1][3] += a.y * b.w;
      acc[2][0] += a.z * b.x; acc[2][1] += a.z * b.y; acc[2][2] += a.z * b.z; acc[2][3] += a.z * b.w;
      acc[3][0] += a.w * b.x; acc[3][1] += a.w * b.y; acc[3][2] += a.w * b.z; acc[3][3] += a.w * b.w;
    }
  }
  #pragma unroll
  for (int r = 0; r < 4; r++) {
    int n = n0 + ty * 4 + r;
    if (n < NN) {
      float dv = dinv[n];
      half4_t h;
      h[0] = (half_t)(acc[r][0] * dv);
      h[1] = (half_t)(acc[r][1] * dv);
      h[2] = (half_t)(acc[r][2] * dv);
      h[3] = (half_t)(acc[r][3] * dv);
      *(half4_t*)&O[(size_t)n * DIM + jb + tx * 4] = h;
    }
  }
}

// ---------------- Aggregation + bias + LayerNorm + ReLU + residual ----------------
// one wave per node (4 nodes / 256-thread block); lane owns feature pair (2l, 2l+1).
// Hh holds dinv[u]*H[u] in fp16; out[v] = dinv[v]*(sum_u Hh[u] + Hh[v]) + bias.
__global__ __launch_bounds__(256) void k_agg(const half2_t* __restrict__ Hh,
                      float* __restrict__ A,
                      const int* __restrict__ rowptr, const int* __restrict__ csrc,
                      const float* __restrict__ dinv,
                      const float* __restrict__ bias, const float* __restrict__ gamma,
                      const float* __restrict__ beta, int res) {
  int lane = threadIdx.x & 63;
  int v = blockIdx.x * 4 + (threadIdx.x >> 6);
  if (v >= NN) return;
  int s0 = rowptr[v], s1 = rowptr[v + 1];
  half2_t hs = Hh[(size_t)v * 64 + lane];          // self-loop term
  float a0 = (float)hs[0], a1 = (float)hs[1];
  int i = s0;
  int head = (s0 + 3) & ~3;
  if (head > s1) head = s1;
  for (; i < head; ++i) {                          // peel to int4 alignment
    half2_t h = Hh[(size_t)csrc[i] * 64 + lane];
    a0 += (float)h[0]; a1 += (float)h[1];
  }
  for (; i + 4 <= s1; i += 4) {                    // 4 gathers in flight
    int4 s4 = *(const int4*)&csrc[i];
    half2_t h0 = Hh[(size_t)s4.x * 64 + lane];
    half2_t h1 = Hh[(size_t)s4.y * 64 + lane];
    half2_t h2 = Hh[(size_t)s4.z * 64 + lane];
    half2_t h3 = Hh[(size_t)s4.w * 64 + lane];
    a0 += (float)h0[0] + (float)h1[0] + (float)h2[0] + (float)h3[0];
    a1 += (float)h0[1] + (float)h1[1] + (float)h2[1] + (float)h3[1];
  }
  for (; i < s1; ++i) {
    half2_t h = Hh[(size_t)csrc[i] * 64 + lane];
    a0 += (float)h[0]; a1 += (float)h[1];
  }
  float dv = dinv[v];
  float2 b2 = *(const float2*)&bias[2 * lane];
  float f0 = a0 * dv + b2.x;
  float f1 = a1 * dv + b2.y;
  // LayerNorm across 128 features held 2/lane in one wave
  float s = f0 + f1, ss = f0 * f0 + f1 * f1;
  #pragma unroll
  for (int o = 1; o < 64; o <<= 1) { s += __shfl_xor(s, o); ss += __shfl_xor(ss, o); }
  float mu = s * (1.f / 128.f);
  float var = ss * (1.f / 128.f) - mu * mu;
  float rs = rsqrtf(var + 1e-5f);
  float2 g2 = *(const float2*)&gamma[2 * lane];
  float2 e2 = *(const float2*)&beta[2 * lane];
  float y0 = fmaxf((f0 - mu) * rs * g2.x + e2.x, 0.f);
  float y1 = fmaxf((f1 - mu) * rs * g2.y + e2.y, 0.f);
  float* Ap = &A[(size_t)v * DIM + 2 * lane];
  if (res) { float2 o2 = *(const float2*)Ap; y0 += o2.x; y1 += o2.y; }
  *(float2*)Ap = make_float2(y0, y1);
}

// ---------------- Global mean pool (batch is sorted) ----------------
__global__ void k_pool(const float* __restrict__ A, const int* __restrict__ batch,
                       float* __restrict__ sums) {
  const int CH = 400;
  int b0 = blockIdx.x * CH;
  int t = threadIdx.x;  // 128
  __shared__ int bb[CH];
  for (int j = t; j < CH; j += 128) {
    int n = b0 + j;
    bb[j] = (n < NN) ? batch[n] : -1;
  }
  __syncthreads();
  float acc = 0.f;
  int cur = -1;
  for (int i = 0; i < CH; i++) {
    int n = b0 + i;
    if (n >= NN) break;
    int g = bb[i];
    if (g != cur) {
      if (cur >= 0) atomicAdd(&sums[cur * DIM + t], acc);
      acc = 0.f; cur = g;
    }
    acc += A[n * DIM + t];
  }
  if (cur >= 0) atomicAdd(&sums[cur * DIM + t], acc);
}

__global__ void k_cnts(const int* __restrict__ batch, float* __restrict__ cnts) {
  int g = threadIdx.x;  // 128
  int lo = 0, hi = NN;
  while (lo < hi) { int mid = (lo + hi) >> 1; if (batch[mid] < g) lo = mid + 1; else hi = mid; }
  int a = lo;
  lo = 0; hi = NN;
  while (lo < hi) { int mid = (lo + hi) >> 1; if (batch[mid] < g + 1) lo = mid + 1; else hi = mid; }
  cnts[g] = (float)(lo - a);
}

// ---------------- Head: relu(pooled @ W1 + b1) @ W2 + b2, sigmoid ----------------
__global__ void k_head(const float* __restrict__ sums, const float* __restrict__ cnts,
                       const float* __restrict__ W1, const float* __restrict__ b1,
                       const float* __restrict__ W2, const float* __restrict__ b2,
                       float* __restrict__ out) {
  int g = blockIdx.x, t = threadIdx.x;  // 64
  __shared__ float p[128];
  float ic = 1.f / fmaxf(cnts[g], 1.f);
  p[t] = sums[g * DIM + t] * ic;
  p[t + 64] = sums[g * DIM + 64 + t] * ic;
  __syncthreads();
  float z = b1[t];
  #pragma unroll 8
  for (int k = 0; k < 128; k++) z += p[k] * W1[k * FCD + t];
  z = fmaxf(z, 0.f);
  float sv = z * W2[t];
  #pragma unroll
  for (int o = 1; o < 64; o <<= 1) sv += __shfl_xor(sv, o);
  if (t == 0) out[g] = 1.f / (1.f + expf(-(sv + b2[0])));
}

extern "C" void kernel_launch(void* const* d_in, const int* in_sizes, int n_in,
                              void* d_out, int out_size, void* d_ws, size_t ws_size,
                              hipStream_t stream) {
  (void)in_sizes; (void)n_in; (void)out_size; (void)ws_size;
  const float* x     = (const float*)d_in[0];
  const int*   ei    = (const int*)d_in[1];
  const int*   batch = (const int*)d_in[2];
  const float* W_in  = (const float*)d_in[3];
  const float* b_in  = (const float*)d_in[4];
  const float* g_in  = (const float*)d_in[5];
  const float* be_in = (const float*)d_in[6];
  const float* W_mid = (const float*)d_in[7];
  const float* b_mid = (const float*)d_in[8];
  const float* g_mid = (const float*)d_in[9];
  const float* be_mid= (const float*)d_in[10];
  const float* W_out = (const float*)d_in[11];
  const float* b_out = (const float*)d_in[12];
  const float* g_out = (const float*)d_in[13];
  const float* be_out= (const float*)d_in[14];
  const float* W1    = (const float*)d_in[15];
  const float* b1    = (const float*)d_in[16];
  const float* W2    = (const float*)d_in[17];
  const float* b2    = (const float*)d_in[18];
  float* out = (float*)d_out;

  // workspace layout (~86 MB)
  char* p = (char*)d_ws;
  auto alloc = [&](size_t bytes) {
    char* r = p;
    p += (bytes + 255) & ~(size_t)255;
    return r;
  };
  float*  A      = (float*)alloc((size_t)NN * DIM * 4);  // node features (fp32)
  half_t* Bh     = (half_t*)alloc((size_t)NN * DIM * 2); // scaled linear output (fp16)
  int*    deg    = (int*)alloc((size_t)NN * 4);
  float*  dinv   = (float*)alloc((size_t)NN * 4);
  int*    rowptr = (int*)alloc((size_t)(NN + 1) * 4);
  int*    fill   = (int*)alloc((size_t)NN * 4);
  int*    csrc   = (int*)alloc((size_t)NE * 4);
  int*    part   = (int*)alloc(1024);
  float*  sums   = (float*)alloc((size_t)NGRAPH * DIM * 4);
  float*  cnts   = (float*)alloc((size_t)NGRAPH * 4);

  const int* rowp = ei;        // sources
  const int* colp = ei + NE;   // targets

  hipMemsetAsync(deg, 0, (size_t)NN * 4, stream);
  hipMemsetAsync(fill, 0, (size_t)NN * 4, stream);
  hipMemsetAsync(sums, 0, (size_t)NGRAPH * DIM * 4, stream);

  k_count<<<(NE + 255) / 256, 256, 0, stream>>>(colp, deg);
  k_dinv<<<(NN + 255) / 256, 256, 0, stream>>>(deg, dinv);
  int nb1 = (NN + 1023) / 1024;  // 98
  k_scan1<<<nb1, 256, 0, stream>>>(deg, rowptr, part);
  k_scan2<<<1, 128, 0, stream>>>(part, rowptr, nb1);
  k_scan3<<<(NN + 255) / 256, 256, 0, stream>>>(rowptr, part);
  k_fill<<<(NE + 255) / 256, 256, 0, stream>>>(rowp, colp, rowptr, fill, csrc);

  int gemm_grid = ((NN + 63) / 64) * 2;
  for (int l = 0; l < 8; l++) {
    const float *Wl, *bl, *gl, *bel;
    if (l == 0)      { Wl = W_in;  bl = b_in;  gl = g_in;  bel = be_in;  }
    else if (l == 7) { Wl = W_out; bl = b_out; gl = g_out; bel = be_out; }
    else             { Wl = W_mid; bl = b_mid; gl = g_mid; bel = be_mid; }
    const float* in = (l == 0) ? x : A;
    k_gemm<<<gemm_grid, 256, 0, stream>>>(in, Wl, dinv, Bh);
    int res = (l >= 2 && l <= 6 && (l % 2 == 0)) ? 1 : 0;
    k_agg<<<(NN + 3) / 4, 256, 0, stream>>>((const half2_t*)Bh, A, rowptr, csrc, dinv,
                                            bl, gl, bel, res);
  }

  k_pool<<<(NN + 399) / 400, 128, 0, stream>>>(A, batch, sums);
  k_cnts<<<1, 128, 0, stream>>>(batch, cnts);
  k_head<<<NGRAPH, 64, 0, stream>>>(sums, cnts, W1, b1, W2, b2, out);
}

// Round 2
// 1302.530 us; speedup vs baseline: 1.3088x; 1.0979x over previous
//
#include <hip/hip_runtime.h>
#include <hip/hip_fp16.h>

#define NN 100000
#define NE 1600000
#define DIM 128
#define NGRAPH 128
#define FCD 64

typedef _Float16 half_t;
typedef _Float16 half2_t __attribute__((ext_vector_type(2)));
typedef _Float16 half4_t __attribute__((ext_vector_type(4)));

// ---------------- CSR build ----------------
__global__ void k_count(const int* __restrict__ col, int* __restrict__ deg) {
  int i = blockIdx.x * 256 + threadIdx.x;
  if (i < NE) atomicAdd(&deg[col[i]], 1);
}

__global__ void k_dinv(const int* __restrict__ deg, float* __restrict__ dinv) {
  int i = blockIdx.x * 256 + threadIdx.x;
  if (i < NN) dinv[i] = rsqrtf((float)(deg[i] + 1));  // +1 self loop
}

// 1024 elems/block, 256 thr x int4. Writes block-local exclusive scan + block sums.
__global__ void k_scan1(const int* __restrict__ deg, int* __restrict__ rowptr,
                        int* __restrict__ part) {
  int b = blockIdx.x, t = threadIdx.x;
  int base = b * 1024 + t * 4;
  int4 v = make_int4(0, 0, 0, 0);
  if (base + 4 <= NN) v = *(const int4*)&deg[base];
  else {
    if (base + 0 < NN) v.x = deg[base + 0];
    if (base + 1 < NN) v.y = deg[base + 1];
    if (base + 2 < NN) v.z = deg[base + 2];
    if (base + 3 < NN) v.w = deg[base + 3];
  }
  int s = v.x + v.y + v.z + v.w;
  int lane = t & 63, w = t >> 6;
  int incl = s;
  for (int o = 1; o < 64; o <<= 1) {
    int u = __shfl_up(incl, o);
    if (lane >= o) incl += u;
  }
  __shared__ int wsum[4];
  if (lane == 63) wsum[w] = incl;
  __syncthreads();
  int woff = 0;
  for (int i = 0; i < w; i++) woff += wsum[i];
  int excl = woff + incl - s;
  int r = excl;
  if (base + 0 < NN) { rowptr[base + 0] = r; r += v.x; }
  if (base + 1 < NN) { rowptr[base + 1] = r; r += v.y; }
  if (base + 2 < NN) { rowptr[base + 2] = r; r += v.z; }
  if (base + 3 < NN) { rowptr[base + 3] = r; r += v.w; }
  if (t == 255) part[b] = woff + incl;
}

__global__ void k_scan2(int* __restrict__ part, int* __restrict__ rowptr, int NB) {
  int t = threadIdx.x;  // 128
  int v = (t < NB) ? part[t] : 0;
  int incl = v;
  int lane = t & 63;
  for (int o = 1; o < 64; o <<= 1) {
    int u = __shfl_up(incl, o);
    if (lane >= o) incl += u;
  }
  __shared__ int w0;
  if (t == 63) w0 = incl;
  __syncthreads();
  if (t >= 64) incl += w0;
  if (t < NB) part[t] = incl - v;  // exclusive
  if (t == 0) rowptr[NN] = NE;
}

__global__ void k_scan3(int* __restrict__ rowptr, const int* __restrict__ part) {
  int i = blockIdx.x * 256 + threadIdx.x;
  if (i < NN) rowptr[i] += part[i >> 10];
}

__global__ void k_fill(const int* __restrict__ row, const int* __restrict__ col,
                       const int* __restrict__ rowptr,
                       int* __restrict__ fill, int* __restrict__ csrc) {
  int e = blockIdx.x * 256 + threadIdx.x;
  if (e >= NE) return;
  int r = row[e], c = col[e];
  int pos = rowptr[c] + atomicAdd(&fill[c], 1);
  csrc[pos] = r;
}

// ---------------- GEMM: O[n][j] = dinv[n] * sum_k X[n][k] * W[k][j], fp16 out ----
// 64x64 tile, 4x4 micro-tile/thread, K staged in two halves of 64.
__global__ __launch_bounds__(256) void k_gemm(const float* __restrict__ X,
                                              const float* __restrict__ W,
                                              const float* __restrict__ dinv,
                                              half_t* __restrict__ O) {
  __shared__ float Xs[64 * 68];  // [k][n], stride 68
  __shared__ float Ws[64 * 64];  // [k][j]
  int bid = blockIdx.x;
  int n0 = (bid >> 1) * 64;
  int jb = (bid & 1) * 64;
  int t = threadIdx.x;
  int tx = t & 15, ty = t >> 4;
  float acc[4][4] = {};
  for (int kb = 0; kb < 128; kb += 64) {
    __syncthreads();
    #pragma unroll
    for (int i = 0; i < 4; i++) {
      int e = t + i * 256;       // 0..1023
      int r = e >> 4;            // node row 0..63
      int kq = (e & 15) * 4;     // k quad
      int n = n0 + r;
      float4 v = make_float4(0.f, 0.f, 0.f, 0.f);
      if (n < NN) v = *(const float4*)&X[n * DIM + kb + kq];
      Xs[(kq + 0) * 68 + r] = v.x;
      Xs[(kq + 1) * 68 + r] = v.y;
      Xs[(kq + 2) * 68 + r] = v.z;
      Xs[(kq + 3) * 68 + r] = v.w;
    }
    #pragma unroll
    for (int i = 0; i < 4; i++) {
      int e = t + i * 256;
      int r = e >> 4;            // k row 0..63
      int jq = (e & 15) * 4;
      *(float4*)&Ws[r * 64 + jq] = *(const float4*)&W[(kb + r) * DIM + jb + jq];
    }
    __syncthreads();
    #pragma unroll 8
    for (int k = 0; k < 64; k++) {
      float4 a = *(const float4*)&Xs[k * 68 + ty * 4];
      float4 b = *(const float4*)&Ws[k * 64 + tx * 4];
      acc[0][0] += a.x * b.x; acc[0][1] += a.x * b.y; acc[0][2] += a.x * b.z; acc[0][3] += a.x * b.w;
      acc[1][0] += a.y * b.x; acc[1][1] += a.y * b.y; acc[1][2] += a.y * b.z; acc[1][3] += a.y * b.w;
      acc[2][0] += a.z * b.x; acc[2][1] += a.z * b.y; acc[2][2] += a.z * b.z; acc[2][3] += a.z * b.w;
      acc[3][0] += a.w * b.x; acc[3][1] += a.w * b.y; acc[3][2] += a.w * b.z; acc[3][3] += a.w * b.w;
    }
  }
  #pragma unroll
  for (int r = 0; r < 4; r++) {
    int n = n0 + ty * 4 + r;
    if (n < NN) {
      float dv = dinv[n];
      half4_t h;
      h[0] = (half_t)(acc[r][0] * dv);
      h[1] = (half_t)(acc[r][1] * dv);
      h[2] = (half_t)(acc[r][2] * dv);
      h[3] = (half_t)(acc[r][3] * dv);
      *(half4_t*)&O[(size_t)n * DIM + jb + tx * 4] = h;
    }
  }
}

// ---------------- Aggregation + bias + LayerNorm + ReLU + residual ----------------
// one wave per node (4 nodes / 256-thread block); lane owns feature pair (2l, 2l+1).
// Hh holds dinv[u]*H[u] in fp16; out[v] = dinv[v]*(sum_u Hh[u] + Hh[v]) + bias.
__global__ __launch_bounds__(256) void k_agg(const half2_t* __restrict__ Hh,
                      float* __restrict__ A,
                      const int* __restrict__ rowptr, const int* __restrict__ csrc,
                      const float* __restrict__ dinv,
                      const float* __restrict__ bias, const float* __restrict__ gamma,
                      const float* __restrict__ beta, int res) {
  int lane = threadIdx.x & 63;
  int v = blockIdx.x * 4 + (threadIdx.x >> 6);
  if (v >= NN) return;
  int s0 = rowptr[v], s1 = rowptr[v + 1];
  half2_t hs = Hh[(size_t)v * 64 + lane];          // self-loop term
  float a0 = (float)hs[0], a1 = (float)hs[1];
  int i = s0;
  int head = (s0 + 3) & ~3;
  if (head > s1) head = s1;
  for (; i < head; ++i) {                          // peel to int4 alignment
    half2_t h = Hh[(size_t)csrc[i] * 64 + lane];
    a0 += (float)h[0]; a1 += (float)h[1];
  }
  for (; i + 4 <= s1; i += 4) {                    // 4 gathers in flight
    int4 s4 = *(const int4*)&csrc[i];
    half2_t h0 = Hh[(size_t)s4.x * 64 + lane];
    half2_t h1 = Hh[(size_t)s4.y * 64 + lane];
    half2_t h2 = Hh[(size_t)s4.z * 64 + lane];
    half2_t h3 = Hh[(size_t)s4.w * 64 + lane];
    a0 += (float)h0[0] + (float)h1[0] + (float)h2[0] + (float)h3[0];
    a1 += (float)h0[1] + (float)h1[1] + (float)h2[1] + (float)h3[1];
  }
  for (; i < s1; ++i) {
    half2_t h = Hh[(size_t)csrc[i] * 64 + lane];
    a0 += (float)h[0]; a1 += (float)h[1];
  }
  float dv = dinv[v];
  float2 b2 = *(const float2*)&bias[2 * lane];
  float f0 = a0 * dv + b2.x;
  float f1 = a1 * dv + b2.y;
  // LayerNorm across 128 features held 2/lane in one wave
  float s = f0 + f1, ss = f0 * f0 + f1 * f1;
  #pragma unroll
  for (int o = 1; o < 64; o <<= 1) { s += __shfl_xor(s, o); ss += __shfl_xor(ss, o); }
  float mu = s * (1.f / 128.f);
  float var = ss * (1.f / 128.f) - mu * mu;
  float rs = rsqrtf(var + 1e-5f);
  float2 g2 = *(const float2*)&gamma[2 * lane];
  float2 e2 = *(const float2*)&beta[2 * lane];
  float y0 = fmaxf((f0 - mu) * rs * g2.x + e2.x, 0.f);
  float y1 = fmaxf((f1 - mu) * rs * g2.y + e2.y, 0.f);
  float* Ap = &A[(size_t)v * DIM + 2 * lane];
  if (res) { float2 o2 = *(const float2*)Ap; y0 += o2.x; y1 += o2.y; }
  *(float2*)Ap = make_float2(y0, y1);
}

// ---------------- Global mean pool (batch is sorted) ----------------
// CH=64 nodes/block, 128 threads (thread t = feature t). Fast path when the
// whole chunk is one graph: 4 independent accumulators keep 4 row-loads in
// flight. Boundary chunks (~8%) take the serial path.
__global__ __launch_bounds__(128) void k_pool(const float* __restrict__ A,
                                              const int* __restrict__ batch,
                                              float* __restrict__ sums) {
  const int CH = 64;
  int b0 = blockIdx.x * CH;
  int t = threadIdx.x;  // 128
  int nmax = NN - b0; if (nmax > CH) nmax = CH;
  __shared__ int bb[CH];
  if (t < CH) bb[t] = (b0 + t < NN) ? batch[b0 + t] : -1;
  __syncthreads();
  int gfirst = bb[0], glast = bb[nmax - 1];
  if (gfirst == glast) {
    float a0 = 0.f, a1 = 0.f, a2 = 0.f, a3 = 0.f;
    int i = 0;
    for (; i + 4 <= nmax; i += 4) {
      a0 += A[(size_t)(b0 + i + 0) * DIM + t];
      a1 += A[(size_t)(b0 + i + 1) * DIM + t];
      a2 += A[(size_t)(b0 + i + 2) * DIM + t];
      a3 += A[(size_t)(b0 + i + 3) * DIM + t];
    }
    for (; i < nmax; ++i) a0 += A[(size_t)(b0 + i) * DIM + t];
    atomicAdd(&sums[gfirst * DIM + t], (a0 + a1) + (a2 + a3));
  } else {
    float acc = 0.f;
    int cur = gfirst;
    for (int i = 0; i < nmax; i++) {
      int g = bb[i];
      if (g != cur) { atomicAdd(&sums[cur * DIM + t], acc); acc = 0.f; cur = g; }
      acc += A[(size_t)(b0 + i) * DIM + t];
    }
    atomicAdd(&sums[cur * DIM + t], acc);
  }
}

__global__ void k_cnts(const int* __restrict__ batch, float* __restrict__ cnts) {
  int g = threadIdx.x;  // 128
  int lo = 0, hi = NN;
  while (lo < hi) { int mid = (lo + hi) >> 1; if (batch[mid] < g) lo = mid + 1; else hi = mid; }
  int a = lo;
  lo = 0; hi = NN;
  while (lo < hi) { int mid = (lo + hi) >> 1; if (batch[mid] < g + 1) lo = mid + 1; else hi = mid; }
  cnts[g] = (float)(lo - a);
}

// ---------------- Head: relu(pooled @ W1 + b1) @ W2 + b2, sigmoid ----------------
__global__ void k_head(const float* __restrict__ sums, const float* __restrict__ cnts,
                       const float* __restrict__ W1, const float* __restrict__ b1,
                       const float* __restrict__ W2, const float* __restrict__ b2,
                       float* __restrict__ out) {
  int g = blockIdx.x, t = threadIdx.x;  // 64
  __shared__ float p[128];
  float ic = 1.f / fmaxf(cnts[g], 1.f);
  p[t] = sums[g * DIM + t] * ic;
  p[t + 64] = sums[g * DIM + 64 + t] * ic;
  __syncthreads();
  float z = b1[t];
  #pragma unroll 8
  for (int k = 0; k < 128; k++) z += p[k] * W1[k * FCD + t];
  z = fmaxf(z, 0.f);
  float sv = z * W2[t];
  #pragma unroll
  for (int o = 1; o < 64; o <<= 1) sv += __shfl_xor(sv, o);
  if (t == 0) out[g] = 1.f / (1.f + expf(-(sv + b2[0])));
}

extern "C" void kernel_launch(void* const* d_in, const int* in_sizes, int n_in,
                              void* d_out, int out_size, void* d_ws, size_t ws_size,
                              hipStream_t stream) {
  (void)in_sizes; (void)n_in; (void)out_size; (void)ws_size;
  const float* x     = (const float*)d_in[0];
  const int*   ei    = (const int*)d_in[1];
  const int*   batch = (const int*)d_in[2];
  const float* W_in  = (const float*)d_in[3];
  const float* b_in  = (const float*)d_in[4];
  const float* g_in  = (const float*)d_in[5];
  const float* be_in = (const float*)d_in[6];
  const float* W_mid = (const float*)d_in[7];
  const float* b_mid = (const float*)d_in[8];
  const float* g_mid = (const float*)d_in[9];
  const float* be_mid= (const float*)d_in[10];
  const float* W_out = (const float*)d_in[11];
  const float* b_out = (const float*)d_in[12];
  const float* g_out = (const float*)d_in[13];
  const float* be_out= (const float*)d_in[14];
  const float* W1    = (const float*)d_in[15];
  const float* b1    = (const float*)d_in[16];
  const float* W2    = (const float*)d_in[17];
  const float* b2    = (const float*)d_in[18];
  float* out = (float*)d_out;

  // workspace layout (~86 MB)
  char* p = (char*)d_ws;
  auto alloc = [&](size_t bytes) {
    char* r = p;
    p += (bytes + 255) & ~(size_t)255;
    return r;
  };
  float*  A      = (float*)alloc((size_t)NN * DIM * 4);  // node features (fp32)
  half_t* Bh     = (half_t*)alloc((size_t)NN * DIM * 2); // scaled linear output (fp16)
  int*    deg    = (int*)alloc((size_t)NN * 4);
  float*  dinv   = (float*)alloc((size_t)NN * 4);
  int*    rowptr = (int*)alloc((size_t)(NN + 1) * 4);
  int*    fill   = (int*)alloc((size_t)NN * 4);
  int*    csrc   = (int*)alloc((size_t)NE * 4);
  int*    part   = (int*)alloc(1024);
  float*  sums   = (float*)alloc((size_t)NGRAPH * DIM * 4);
  float*  cnts   = (float*)alloc((size_t)NGRAPH * 4);

  const int* rowp = ei;        // sources
  const int* colp = ei + NE;   // targets

  hipMemsetAsync(deg, 0, (size_t)NN * 4, stream);
  hipMemsetAsync(fill, 0, (size_t)NN * 4, stream);
  hipMemsetAsync(sums, 0, (size_t)NGRAPH * DIM * 4, stream);

  k_count<<<(NE + 255) / 256, 256, 0, stream>>>(colp, deg);
  k_dinv<<<(NN + 255) / 256, 256, 0, stream>>>(deg, dinv);
  int nb1 = (NN + 1023) / 1024;  // 98
  k_scan1<<<nb1, 256, 0, stream>>>(deg, rowptr, part);
  k_scan2<<<1, 128, 0, stream>>>(part, rowptr, nb1);
  k_scan3<<<(NN + 255) / 256, 256, 0, stream>>>(rowptr, part);
  k_fill<<<(NE + 255) / 256, 256, 0, stream>>>(rowp, colp, rowptr, fill, csrc);

  int gemm_grid = ((NN + 63) / 64) * 2;
  for (int l = 0; l < 8; l++) {
    const float *Wl, *bl, *gl, *bel;
    if (l == 0)      { Wl = W_in;  bl = b_in;  gl = g_in;  bel = be_in;  }
    else if (l == 7) { Wl = W_out; bl = b_out; gl = g_out; bel = be_out; }
    else             { Wl = W_mid; bl = b_mid; gl = g_mid; bel = be_mid; }
    const float* in = (l == 0) ? x : A;
    k_gemm<<<gemm_grid, 256, 0, stream>>>(in, Wl, dinv, Bh);
    int res = (l >= 2 && l <= 6 && (l % 2 == 0)) ? 1 : 0;
    k_agg<<<(NN + 3) / 4, 256, 0, stream>>>((const half2_t*)Bh, A, rowptr, csrc, dinv,
                                            bl, gl, bel, res);
  }

  k_pool<<<(NN + 63) / 64, 128, 0, stream>>>(A, batch, sums);
  k_cnts<<<1, 128, 0, stream>>>(batch, cnts);
  k_head<<<NGRAPH, 64, 0, stream>>>(sums, cnts, W1, b1, W2, b2, out);
}

// Round 3
// 1178.404 us; speedup vs baseline: 1.4466x; 1.1053x over previous
//
#include <hip/hip_runtime.h>
#include <hip/hip_fp16.h>

#define NN 100000
#define NE 1600000
#define DIM 128
#define NGRAPH 128
#define FCD 64

#define NBK 391          // buckets of 256 target nodes: (NN+255)>>8
#define ECH 8192         // edges per pass-A chunk
#define NCH 196          // (NE + ECH - 1) / ECH
#define ECAP 8192        // pass-B per-bucket LDS capacity (avg ~4092, max ~4400)

typedef _Float16 half_t;
typedef _Float16 half2_t __attribute__((ext_vector_type(2)));
typedef _Float16 half4_t __attribute__((ext_vector_type(4)));

// ---------------- CSR build: two-level counting sort ----------------
// Pass A: chunk-local bucket sort by (target >> 8). Scattered writes stay inside
// the block's private 32KB staging window -> L2 merges to full lines.
__global__ __launch_bounds__(256) void k_bucketA(const int* __restrict__ row,
                                                 const int* __restrict__ col,
                                                 int* __restrict__ staged,
                                                 int* __restrict__ offmat,
                                                 int* __restrict__ gtot) {
  __shared__ int hist[NBK];
  __shared__ int sc[512];
  __shared__ int off[NBK + 1];
  __shared__ int fill[NBK];
  int b = blockIdx.x, t = threadIdx.x;
  int e0 = b * ECH;
  int n = NE - e0; if (n > ECH) n = ECH;
  for (int j = t; j < NBK; j += 256) { hist[j] = 0; fill[j] = 0; }
  __syncthreads();
  for (int i = t; i < n; i += 256) atomicAdd(&hist[col[e0 + i] >> 8], 1);
  __syncthreads();
  sc[t] = (t < NBK) ? hist[t] : 0;
  sc[t + 256] = (t + 256 < NBK) ? hist[t + 256] : 0;
  __syncthreads();
  #pragma unroll
  for (int o = 1; o < 512; o <<= 1) {   // Hillis-Steele inclusive scan, 512 wide
    int a0 = (t >= o) ? sc[t - o] : 0;
    int a1 = (t + 256 >= o) ? sc[t + 256 - o] : 0;
    __syncthreads();
    sc[t] += a0; sc[t + 256] += a1;
    __syncthreads();
  }
  if (t == 0) off[0] = 0;
  for (int j = t; j < NBK; j += 256) off[j + 1] = sc[j];
  for (int j = t; j < NBK; j += 256) if (hist[j]) atomicAdd(&gtot[j], hist[j]);
  __syncthreads();
  for (int j = t; j < NBK + 1; j += 256) offmat[b * (NBK + 1) + j] = off[j];
  for (int i = t; i < n; i += 256) {
    int c = col[e0 + i], r = row[e0 + i];
    int bkt = c >> 8;
    int pos = off[bkt] + atomicAdd(&fill[bkt], 1);
    staged[e0 + pos] = (r << 8) | (c & 255);   // pack src(17b) | target_low(8b)
  }
}

// Scan bucket totals -> global bucket bases.
__global__ void k_bsum(const int* __restrict__ gtot, int* __restrict__ gbase,
                       int* __restrict__ rowptr) {
  __shared__ int sc[512];
  int t = threadIdx.x;  // 256
  sc[t] = (t < NBK) ? gtot[t] : 0;
  sc[t + 256] = (t + 256 < NBK) ? gtot[t + 256] : 0;
  __syncthreads();
  #pragma unroll
  for (int o = 1; o < 512; o <<= 1) {
    int a0 = (t >= o) ? sc[t - o] : 0;
    int a1 = (t + 256 >= o) ? sc[t + 256 - o] : 0;
    __syncthreads();
    sc[t] += a0; sc[t + 256] += a1;
    __syncthreads();
  }
  if (t == 0) { gbase[0] = 0; rowptr[NN] = NE; }
  for (int j = t; j < NBK; j += 256) gbase[j + 1] = sc[j];
}

// Pass B: one block per bucket (256 target nodes). Gathers the bucket's edges
// from all chunk segments into LDS, builds per-node CSR, emits rowptr + dinv +
// csrc. csrc scatter stays inside the bucket's contiguous output window.
__global__ __launch_bounds__(256) void k_csrB(const int* __restrict__ staged,
                                              const int* __restrict__ offmat,
                                              const int* __restrict__ gbase,
                                              int* __restrict__ rowptr,
                                              float* __restrict__ dinv,
                                              int* __restrict__ csrc) {
  __shared__ int pay[ECAP];
  __shared__ int csn[256];
  __shared__ int nhist[256];
  __shared__ int nscan[256];
  __shared__ int nb[256];
  __shared__ int nfill[256];
  int bkt = blockIdx.x, t = threadIdx.x;
  int gb = gbase[bkt];
  int off = 0, cnt = 0;
  if (t < NCH) {
    int base = t * (NBK + 1) + bkt;
    off = offmat[base];
    cnt = offmat[base + 1] - off;
  }
  csn[t] = cnt;
  __syncthreads();
  #pragma unroll
  for (int o = 1; o < 256; o <<= 1) {
    int a = (t >= o) ? csn[t - o] : 0;
    __syncthreads();
    csn[t] += a;
    __syncthreads();
  }
  int lb = csn[t] - cnt;
  int total = csn[255];
  if (t < NCH) {
    const int* src = staged + t * ECH + off;
    for (int i = 0; i < cnt; i++) pay[lb + i] = src[i];
  }
  nhist[t] = 0; nfill[t] = 0;
  __syncthreads();
  for (int i = t; i < total; i += 256) atomicAdd(&nhist[pay[i] & 255], 1);
  __syncthreads();
  nscan[t] = nhist[t];
  __syncthreads();
  #pragma unroll
  for (int o = 1; o < 256; o <<= 1) {
    int a = (t >= o) ? nscan[t - o] : 0;
    __syncthreads();
    nscan[t] += a;
    __syncthreads();
  }
  nb[t] = nscan[t] - nhist[t];
  int v = bkt * 256 + t;
  if (v < NN) {
    rowptr[v] = gb + nb[t];
    dinv[v] = rsqrtf((float)(nhist[t] + 1));   // +1 self loop
  }
  __syncthreads();
  for (int i = t; i < total; i += 256) {
    int p = pay[i];
    int cl = p & 255;
    int pos = nb[cl] + atomicAdd(&nfill[cl], 1);
    csrc[gb + pos] = p >> 8;
  }
}

// ---------------- GEMM: O[n][j] = dinv[n] * sum_k X[n][k] * W[k][j], fp16 out ----
__global__ __launch_bounds__(256) void k_gemm(const float* __restrict__ X,
                                              const float* __restrict__ W,
                                              const float* __restrict__ dinv,
                                              half_t* __restrict__ O) {
  __shared__ float Xs[64 * 68];  // [k][n], stride 68
  __shared__ float Ws[64 * 64];  // [k][j]
  int bid = blockIdx.x;
  int n0 = (bid >> 1) * 64;
  int jb = (bid & 1) * 64;
  int t = threadIdx.x;
  int tx = t & 15, ty = t >> 4;
  float acc[4][4] = {};
  for (int kb = 0; kb < 128; kb += 64) {
    __syncthreads();
    #pragma unroll
    for (int i = 0; i < 4; i++) {
      int e = t + i * 256;       // 0..1023
      int r = e >> 4;            // node row 0..63
      int kq = (e & 15) * 4;     // k quad
      int n = n0 + r;
      float4 v = make_float4(0.f, 0.f, 0.f, 0.f);
      if (n < NN) v = *(const float4*)&X[n * DIM + kb + kq];
      Xs[(kq + 0) * 68 + r] = v.x;
      Xs[(kq + 1) * 68 + r] = v.y;
      Xs[(kq + 2) * 68 + r] = v.z;
      Xs[(kq + 3) * 68 + r] = v.w;
    }
    #pragma unroll
    for (int i = 0; i < 4; i++) {
      int e = t + i * 256;
      int r = e >> 4;            // k row 0..63
      int jq = (e & 15) * 4;
      *(float4*)&Ws[r * 64 + jq] = *(const float4*)&W[(kb + r) * DIM + jb + jq];
    }
    __syncthreads();
    #pragma unroll 8
    for (int k = 0; k < 64; k++) {
      float4 a = *(const float4*)&Xs[k * 68 + ty * 4];
      float4 b = *(const float4*)&Ws[k * 64 + tx * 4];
      acc[0][0] += a.x * b.x; acc[0][1] += a.x * b.y; acc[0][2] += a.x * b.z; acc[0][3] += a.x * b.w;
      acc[1][0] += a.y * b.x; acc[1][1] += a.y * b.y; acc[1][2] += a.y * b.z; acc[1][3] += a.y * b.w;
      acc[2][0] += a.z * b.x; acc[2][1] += a.z * b.y; acc[2][2] += a.z * b.z; acc[2][3] += a.z * b.w;
      acc[3][0] += a.w * b.x; acc[3][1] += a.w * b.y; acc[3][2] += a.w * b.z; acc[3][3] += a.w * b.w;
    }
  }
  #pragma unroll
  for (int r = 0; r < 4; r++) {
    int n = n0 + ty * 4 + r;
    if (n < NN) {
      float dv = dinv[n];
      half4_t h;
      h[0] = (half_t)(acc[r][0] * dv);
      h[1] = (half_t)(acc[r][1] * dv);
      h[2] = (half_t)(acc[r][2] * dv);
      h[3] = (half_t)(acc[r][3] * dv);
      *(half4_t*)&O[(size_t)n * DIM + jb + tx * 4] = h;
    }
  }
}

// ---------------- Aggregation + bias + LayerNorm + ReLU + residual ----------------
__global__ __launch_bounds__(256) void k_agg(const half2_t* __restrict__ Hh,
                      float* __restrict__ A,
                      const int* __restrict__ rowptr, const int* __restrict__ csrc,
                      const float* __restrict__ dinv,
                      const float* __restrict__ bias, const float* __restrict__ gamma,
                      const float* __restrict__ beta, int res) {
  int lane = threadIdx.x & 63;
  int v = blockIdx.x * 4 + (threadIdx.x >> 6);
  if (v >= NN) return;
  int s0 = rowptr[v], s1 = rowptr[v + 1];
  half2_t hs = Hh[(size_t)v * 64 + lane];          // self-loop term
  float a0 = (float)hs[0], a1 = (float)hs[1];
  int i = s0;
  int head = (s0 + 3) & ~3;
  if (head > s1) head = s1;
  for (; i < head; ++i) {                          // peel to int4 alignment
    half2_t h = Hh[(size_t)csrc[i] * 64 + lane];
    a0 += (float)h[0]; a1 += (float)h[1];
  }
  for (; i + 4 <= s1; i += 4) {                    // 4 gathers in flight
    int4 s4 = *(const int4*)&csrc[i];
    half2_t h0 = Hh[(size_t)s4.x * 64 + lane];
    half2_t h1 = Hh[(size_t)s4.y * 64 + lane];
    half2_t h2 = Hh[(size_t)s4.z * 64 + lane];
    half2_t h3 = Hh[(size_t)s4.w * 64 + lane];
    a0 += (float)h0[0] + (float)h1[0] + (float)h2[0] + (float)h3[0];
    a1 += (float)h0[1] + (float)h1[1] + (float)h2[1] + (float)h3[1];
  }
  for (; i < s1; ++i) {
    half2_t h = Hh[(size_t)csrc[i] * 64 + lane];
    a0 += (float)h[0]; a1 += (float)h[1];
  }
  float dv = dinv[v];
  float2 b2 = *(const float2*)&bias[2 * lane];
  float f0 = a0 * dv + b2.x;
  float f1 = a1 * dv + b2.y;
  float s = f0 + f1, ss = f0 * f0 + f1 * f1;
  #pragma unroll
  for (int o = 1; o < 64; o <<= 1) { s += __shfl_xor(s, o); ss += __shfl_xor(ss, o); }
  float mu = s * (1.f / 128.f);
  float var = ss * (1.f / 128.f) - mu * mu;
  float rs = rsqrtf(var + 1e-5f);
  float2 g2 = *(const float2*)&gamma[2 * lane];
  float2 e2 = *(const float2*)&beta[2 * lane];
  float y0 = fmaxf((f0 - mu) * rs * g2.x + e2.x, 0.f);
  float y1 = fmaxf((f1 - mu) * rs * g2.y + e2.y, 0.f);
  float* Ap = &A[(size_t)v * DIM + 2 * lane];
  if (res) { float2 o2 = *(const float2*)Ap; y0 += o2.x; y1 += o2.y; }
  *(float2*)Ap = make_float2(y0, y1);
}

// ---------------- Global mean pool (batch is sorted) ----------------
__global__ __launch_bounds__(128) void k_pool(const float* __restrict__ A,
                                              const int* __restrict__ batch,
                                              float* __restrict__ sums) {
  const int CH = 64;
  int b0 = blockIdx.x * CH;
  int t = threadIdx.x;  // 128
  int nmax = NN - b0; if (nmax > CH) nmax = CH;
  __shared__ int bb[CH];
  if (t < CH) bb[t] = (b0 + t < NN) ? batch[b0 + t] : -1;
  __syncthreads();
  int gfirst = bb[0], glast = bb[nmax - 1];
  if (gfirst == glast) {
    float a0 = 0.f, a1 = 0.f, a2 = 0.f, a3 = 0.f;
    int i = 0;
    for (; i + 4 <= nmax; i += 4) {
      a0 += A[(size_t)(b0 + i + 0) * DIM + t];
      a1 += A[(size_t)(b0 + i + 1) * DIM + t];
      a2 += A[(size_t)(b0 + i + 2) * DIM + t];
      a3 += A[(size_t)(b0 + i + 3) * DIM + t];
    }
    for (; i < nmax; ++i) a0 += A[(size_t)(b0 + i) * DIM + t];
    atomicAdd(&sums[gfirst * DIM + t], (a0 + a1) + (a2 + a3));
  } else {
    float acc = 0.f;
    int cur = gfirst;
    for (int i = 0; i < nmax; i++) {
      int g = bb[i];
      if (g != cur) { atomicAdd(&sums[cur * DIM + t], acc); acc = 0.f; cur = g; }
      acc += A[(size_t)(b0 + i) * DIM + t];
    }
    atomicAdd(&sums[cur * DIM + t], acc);
  }
}

__global__ void k_cnts(const int* __restrict__ batch, float* __restrict__ cnts) {
  int g = threadIdx.x;  // 128
  int lo = 0, hi = NN;
  while (lo < hi) { int mid = (lo + hi) >> 1; if (batch[mid] < g) lo = mid + 1; else hi = mid; }
  int a = lo;
  lo = 0; hi = NN;
  while (lo < hi) { int mid = (lo + hi) >> 1; if (batch[mid] < g + 1) lo = mid + 1; else hi = mid; }
  cnts[g] = (float)(lo - a);
}

// ---------------- Head ----------------
__global__ void k_head(const float* __restrict__ sums, const float* __restrict__ cnts,
                       const float* __restrict__ W1, const float* __restrict__ b1,
                       const float* __restrict__ W2, const float* __restrict__ b2,
                       float* __restrict__ out) {
  int g = blockIdx.x, t = threadIdx.x;  // 64
  __shared__ float p[128];
  float ic = 1.f / fmaxf(cnts[g], 1.f);
  p[t] = sums[g * DIM + t] * ic;
  p[t + 64] = sums[g * DIM + 64 + t] * ic;
  __syncthreads();
  float z = b1[t];
  #pragma unroll 8
  for (int k = 0; k < 128; k++) z += p[k] * W1[k * FCD + t];
  z = fmaxf(z, 0.f);
  float sv = z * W2[t];
  #pragma unroll
  for (int o = 1; o < 64; o <<= 1) sv += __shfl_xor(sv, o);
  if (t == 0) out[g] = 1.f / (1.f + expf(-(sv + b2[0])));
}

extern "C" void kernel_launch(void* const* d_in, const int* in_sizes, int n_in,
                              void* d_out, int out_size, void* d_ws, size_t ws_size,
                              hipStream_t stream) {
  (void)in_sizes; (void)n_in; (void)out_size; (void)ws_size;
  const float* x     = (const float*)d_in[0];
  const int*   ei    = (const int*)d_in[1];
  const int*   batch = (const int*)d_in[2];
  const float* W_in  = (const float*)d_in[3];
  const float* b_in  = (const float*)d_in[4];
  const float* g_in  = (const float*)d_in[5];
  const float* be_in = (const float*)d_in[6];
  const float* W_mid = (const float*)d_in[7];
  const float* b_mid = (const float*)d_in[8];
  const float* g_mid = (const float*)d_in[9];
  const float* be_mid= (const float*)d_in[10];
  const float* W_out = (const float*)d_in[11];
  const float* b_out = (const float*)d_in[12];
  const float* g_out = (const float*)d_in[13];
  const float* be_out= (const float*)d_in[14];
  const float* W1    = (const float*)d_in[15];
  const float* b1    = (const float*)d_in[16];
  const float* W2    = (const float*)d_in[17];
  const float* b2    = (const float*)d_in[18];
  float* out = (float*)d_out;

  // workspace layout (~91 MB)
  char* p = (char*)d_ws;
  auto alloc = [&](size_t bytes) {
    char* r = p;
    p += (bytes + 255) & ~(size_t)255;
    return r;
  };
  float*  A      = (float*)alloc((size_t)NN * DIM * 4);   // node features (fp32)
  half_t* Bh     = (half_t*)alloc((size_t)NN * DIM * 2);  // scaled linear output (fp16)
  float*  dinv   = (float*)alloc((size_t)NN * 4);
  int*    rowptr = (int*)alloc((size_t)(NN + 1) * 4);
  int*    csrc   = (int*)alloc((size_t)NE * 4);
  int*    staged = (int*)alloc((size_t)NCH * ECH * 4);    // bucket-sorted chunks
  int*    offmat = (int*)alloc((size_t)NCH * (NBK + 1) * 4);
  int*    gtot   = (int*)alloc((size_t)(NBK + 1) * 4);
  int*    gbase  = (int*)alloc((size_t)(NBK + 1) * 4);
  float*  sums   = (float*)alloc((size_t)NGRAPH * DIM * 4);
  float*  cnts   = (float*)alloc((size_t)NGRAPH * 4);

  const int* rowp = ei;        // sources
  const int* colp = ei + NE;   // targets

  hipMemsetAsync(gtot, 0, (size_t)(NBK + 1) * 4, stream);
  hipMemsetAsync(sums, 0, (size_t)NGRAPH * DIM * 4, stream);

  k_bucketA<<<NCH, 256, 0, stream>>>(rowp, colp, staged, offmat, gtot);
  k_bsum<<<1, 256, 0, stream>>>(gtot, gbase, rowptr);
  k_csrB<<<NBK, 256, 0, stream>>>(staged, offmat, gbase, rowptr, dinv, csrc);

  int gemm_grid = ((NN + 63) / 64) * 2;
  for (int l = 0; l < 8; l++) {
    const float *Wl, *bl, *gl, *bel;
    if (l == 0)      { Wl = W_in;  bl = b_in;  gl = g_in;  bel = be_in;  }
    else if (l == 7) { Wl = W_out; bl = b_out; gl = g_out; bel = be_out; }
    else             { Wl = W_mid; bl = b_mid; gl = g_mid; bel = be_mid; }
    const float* in = (l == 0) ? x : A;
    k_gemm<<<gemm_grid, 256, 0, stream>>>(in, Wl, dinv, Bh);
    int res = (l >= 2 && l <= 6 && (l % 2 == 0)) ? 1 : 0;
    k_agg<<<(NN + 3) / 4, 256, 0, stream>>>((const half2_t*)Bh, A, rowptr, csrc, dinv,
                                            bl, gl, bel, res);
  }

  k_pool<<<(NN + 63) / 64, 128, 0, stream>>>(A, batch, sums);
  k_cnts<<<1, 128, 0, stream>>>(batch, cnts);
  k_head<<<NGRAPH, 64, 0, stream>>>(sums, cnts, W1, b1, W2, b2, out);
}

// Round 5
// 1105.469 us; speedup vs baseline: 1.5421x; 1.0660x over previous
//
#include <hip/hip_runtime.h>
#include <hip/hip_fp16.h>

#define NN 100000
#define NE 1600000
#define DIM 128
#define NGRAPH 128
#define FCD 64

#define NBK 391          // buckets of 256 target nodes: (NN+255)>>8
#define ECH 8192         // edges per pass-A chunk
#define NCH 196          // (NE + ECH - 1) / ECH
#define ECAP 8192        // pass-B per-bucket LDS capacity (avg ~4092, max ~4400)

typedef _Float16 half_t;
typedef _Float16 half2_t __attribute__((ext_vector_type(2)));
typedef _Float16 half4_t __attribute__((ext_vector_type(4)));

__device__ inline half2_t u2h(unsigned u) { union { unsigned u; half2_t h; } x; x.u = u; return x.h; }
__device__ inline unsigned h2u(half2_t h) { union { unsigned u; half2_t h; } x; x.h = h; return x.u; }

#if defined(__has_builtin)
#if __has_builtin(__builtin_amdgcn_fdot2)
#define HAS_FDOT2 1
#endif
#endif
#ifndef HAS_FDOT2
#define HAS_FDOT2 0
#endif

__device__ inline float dot2(half2_t a, half2_t b, float c) {
#if HAS_FDOT2
  return __builtin_amdgcn_fdot2(a, b, c, false);
#else
  return c + (float)a[0] * (float)b[0] + (float)a[1] * (float)b[1];
#endif
}

// ---------------- CSR build: two-level counting sort ----------------
__global__ __launch_bounds__(256) void k_bucketA(const int* __restrict__ row,
                                                 const int* __restrict__ col,
                                                 int* __restrict__ staged,
                                                 int* __restrict__ offmat,
                                                 int* __restrict__ gtot) {
  __shared__ int hist[NBK];
  __shared__ int sc[512];
  __shared__ int off[NBK + 1];
  __shared__ int fill[NBK];
  int b = blockIdx.x, t = threadIdx.x;
  int e0 = b * ECH;
  int n = NE - e0; if (n > ECH) n = ECH;
  for (int j = t; j < NBK; j += 256) { hist[j] = 0; fill[j] = 0; }
  __syncthreads();
  for (int i = t; i < n; i += 256) atomicAdd(&hist[col[e0 + i] >> 8], 1);
  __syncthreads();
  sc[t] = (t < NBK) ? hist[t] : 0;
  sc[t + 256] = (t + 256 < NBK) ? hist[t + 256] : 0;
  __syncthreads();
  #pragma unroll
  for (int o = 1; o < 512; o <<= 1) {
    int a0 = (t >= o) ? sc[t - o] : 0;
    int a1 = (t + 256 >= o) ? sc[t + 256 - o] : 0;
    __syncthreads();
    sc[t] += a0; sc[t + 256] += a1;
    __syncthreads();
  }
  if (t == 0) off[0] = 0;
  for (int j = t; j < NBK; j += 256) off[j + 1] = sc[j];
  for (int j = t; j < NBK; j += 256) if (hist[j]) atomicAdd(&gtot[j], hist[j]);
  __syncthreads();
  for (int j = t; j < NBK + 1; j += 256) offmat[b * (NBK + 1) + j] = off[j];
  for (int i = t; i < n; i += 256) {
    int c = col[e0 + i], r = row[e0 + i];
    int bkt = c >> 8;
    int pos = off[bkt] + atomicAdd(&fill[bkt], 1);
    staged[e0 + pos] = (r << 8) | (c & 255);
  }
}

__global__ void k_bsum(const int* __restrict__ gtot, int* __restrict__ gbase,
                       int* __restrict__ rowptr) {
  __shared__ int sc[512];
  int t = threadIdx.x;  // 256
  sc[t] = (t < NBK) ? gtot[t] : 0;
  sc[t + 256] = (t + 256 < NBK) ? gtot[t + 256] : 0;
  __syncthreads();
  #pragma unroll
  for (int o = 1; o < 512; o <<= 1) {
    int a0 = (t >= o) ? sc[t - o] : 0;
    int a1 = (t + 256 >= o) ? sc[t + 256 - o] : 0;
    __syncthreads();
    sc[t] += a0; sc[t + 256] += a1;
    __syncthreads();
  }
  if (t == 0) { gbase[0] = 0; rowptr[NN] = NE; }
  for (int j = t; j < NBK; j += 256) gbase[j + 1] = sc[j];
}

__global__ __launch_bounds__(256) void k_csrB(const int* __restrict__ staged,
                                              const int* __restrict__ offmat,
                                              const int* __restrict__ gbase,
                                              int* __restrict__ rowptr,
                                              float* __restrict__ dinv,
                                              int* __restrict__ csrc) {
  __shared__ int pay[ECAP];
  __shared__ int csn[256];
  __shared__ int nhist[256];
  __shared__ int nscan[256];
  __shared__ int nb[256];
  __shared__ int nfill[256];
  int bkt = blockIdx.x, t = threadIdx.x;
  int gb = gbase[bkt];
  int off = 0, cnt = 0;
  if (t < NCH) {
    int base = t * (NBK + 1) + bkt;
    off = offmat[base];
    cnt = offmat[base + 1] - off;
  }
  csn[t] = cnt;
  __syncthreads();
  #pragma unroll
  for (int o = 1; o < 256; o <<= 1) {
    int a = (t >= o) ? csn[t - o] : 0;
    __syncthreads();
    csn[t] += a;
    __syncthreads();
  }
  int lb = csn[t] - cnt;
  int total = csn[255];
  if (t < NCH) {
    const int* src = staged + t * ECH + off;
    for (int i = 0; i < cnt; i++) pay[lb + i] = src[i];
  }
  nhist[t] = 0; nfill[t] = 0;
  __syncthreads();
  for (int i = t; i < total; i += 256) atomicAdd(&nhist[pay[i] & 255], 1);
  __syncthreads();
  nscan[t] = nhist[t];
  __syncthreads();
  #pragma unroll
  for (int o = 1; o < 256; o <<= 1) {
    int a = (t >= o) ? nscan[t - o] : 0;
    __syncthreads();
    nscan[t] += a;
    __syncthreads();
  }
  nb[t] = nscan[t] - nhist[t];
  int v = bkt * 256 + t;
  if (v < NN) {
    rowptr[v] = gb + nb[t];
    dinv[v] = rsqrtf((float)(nhist[t] + 1));   // +1 self loop
  }
  __syncthreads();
  for (int i = t; i < total; i += 256) {
    int p = pay[i];
    int cl = p & 255;
    int pos = nb[cl] + atomicAdd(&nfill[cl], 1);
    csrc[gb + pos] = p >> 8;
  }
}

// ---------------- x fp32 -> fp16 (layer-0 input only) ----------------
__global__ void k_cvt(const float* __restrict__ x, half_t* __restrict__ Xh) {
  int i = blockIdx.x * 256 + threadIdx.x;
  if ((size_t)i * 4 < (size_t)NN * DIM) {
    float4 v = *(const float4*)&x[(size_t)i * 4];
    half4_t h; h[0] = (half_t)v.x; h[1] = (half_t)v.y; h[2] = (half_t)v.z; h[3] = (half_t)v.w;
    *(half4_t*)&Xh[(size_t)i * 4] = h;
  }
}

// ---------------- GEMM: O[n][j] = dinv[n] * sum_k X[n][k] * W[k][j] ----------------
// dot2 fp16 compute, fp32 accumulate. X is fp16 (layer 0) or fp32 (layers 1-7,
// converted to fp16 in-register during LDS staging). fp16 out.
__global__ __launch_bounds__(256) void k_gemm(const void* __restrict__ X, int xIsHalf,
                                              const float* __restrict__ W,
                                              const float* __restrict__ dinv,
                                              half_t* __restrict__ O) {
  __shared__ unsigned Xs[32 * 68];  // [k-pair][row] half2-as-uint, stride 68
  __shared__ unsigned Ws[32 * 68];  // [k-pair][col] half2 (W[k][j], W[k+1][j])
  int bid = blockIdx.x;
  int n0 = (bid >> 1) * 64;
  int jb = (bid & 1) * 64;
  int t = threadIdx.x;
  int tx = t & 15, ty = t >> 4;
  float acc[4][4] = {};
  for (int kb = 0; kb < 128; kb += 64) {
    __syncthreads();
    if (xIsHalf) {
      const half_t* Xp = (const half_t*)X;
      int row = t >> 2, seg = t & 3;   // row 0..63, 16B segment (8 halfs) of 64-k chunk
      int n = n0 + row;
      uint4 v = make_uint4(0, 0, 0, 0);
      if (n < NN) v = *(const uint4*)&Xp[(size_t)n * DIM + kb + seg * 8];
      int kp0 = seg * 4;
      Xs[(kp0 + 0) * 68 + row] = v.x;
      Xs[(kp0 + 1) * 68 + row] = v.y;
      Xs[(kp0 + 2) * 68 + row] = v.z;
      Xs[(kp0 + 3) * 68 + row] = v.w;
    } else {
      const float* Xp = (const float*)X;
      #pragma unroll
      for (int i = 0; i < 4; i++) {
        int e = t + i * 256;       // 0..1023
        int row = e >> 4;          // node row 0..63
        int kq = (e & 15) * 4;     // k offset in chunk, 0..60
        int n = n0 + row;
        float4 v = make_float4(0.f, 0.f, 0.f, 0.f);
        if (n < NN) v = *(const float4*)&Xp[(size_t)n * DIM + kb + kq];
        half2_t p0; p0[0] = (half_t)v.x; p0[1] = (half_t)v.y;
        half2_t p1; p1[0] = (half_t)v.z; p1[1] = (half_t)v.w;
        int kp = kq >> 1;
        Xs[(kp + 0) * 68 + row] = h2u(p0);
        Xs[(kp + 1) * 68 + row] = h2u(p1);
      }
    }
    #pragma unroll
    for (int i = 0; i < 2; i++) {
      int e = t + i * 256;      // 0..511
      int kp = e >> 4;          // 0..31
      int jq = (e & 15) * 4;
      float4 a = *(const float4*)&W[(size_t)(kb + 2 * kp) * DIM + jb + jq];
      float4 b = *(const float4*)&W[(size_t)(kb + 2 * kp + 1) * DIM + jb + jq];
      half2_t p0; p0[0] = (half_t)a.x; p0[1] = (half_t)b.x;
      half2_t p1; p1[0] = (half_t)a.y; p1[1] = (half_t)b.y;
      half2_t p2; p2[0] = (half_t)a.z; p2[1] = (half_t)b.z;
      half2_t p3; p3[0] = (half_t)a.w; p3[1] = (half_t)b.w;
      *(uint4*)&Ws[kp * 68 + jq] = make_uint4(h2u(p0), h2u(p1), h2u(p2), h2u(p3));
    }
    __syncthreads();
    #pragma unroll 8
    for (int kp = 0; kp < 32; kp++) {
      uint4 au = *(const uint4*)&Xs[kp * 68 + ty * 4];
      uint4 bu = *(const uint4*)&Ws[kp * 68 + tx * 4];
      half2_t a0 = u2h(au.x), a1 = u2h(au.y), a2 = u2h(au.z), a3 = u2h(au.w);
      half2_t b0 = u2h(bu.x), b1 = u2h(bu.y), b2 = u2h(bu.z), b3 = u2h(bu.w);
      acc[0][0] = dot2(a0, b0, acc[0][0]); acc[0][1] = dot2(a0, b1, acc[0][1]);
      acc[0][2] = dot2(a0, b2, acc[0][2]); acc[0][3] = dot2(a0, b3, acc[0][3]);
      acc[1][0] = dot2(a1, b0, acc[1][0]); acc[1][1] = dot2(a1, b1, acc[1][1]);
      acc[1][2] = dot2(a1, b2, acc[1][2]); acc[1][3] = dot2(a1, b3, acc[1][3]);
      acc[2][0] = dot2(a2, b0, acc[2][0]); acc[2][1] = dot2(a2, b1, acc[2][1]);
      acc[2][2] = dot2(a2, b2, acc[2][2]); acc[2][3] = dot2(a2, b3, acc[2][3]);
      acc[3][0] = dot2(a3, b0, acc[3][0]); acc[3][1] = dot2(a3, b1, acc[3][1]);
      acc[3][2] = dot2(a3, b2, acc[3][2]); acc[3][3] = dot2(a3, b3, acc[3][3]);
    }
  }
  #pragma unroll
  for (int r = 0; r < 4; r++) {
    int n = n0 + ty * 4 + r;
    if (n < NN) {
      float dv = dinv[n];
      half4_t h;
      h[0] = (half_t)(acc[r][0] * dv);
      h[1] = (half_t)(acc[r][1] * dv);
      h[2] = (half_t)(acc[r][2] * dv);
      h[3] = (half_t)(acc[r][3] * dv);
      *(half4_t*)&O[(size_t)n * DIM + jb + tx * 4] = h;
    }
  }
}

// ---------------- Aggregation + bias + LayerNorm + ReLU + residual ----------------
// one wave per node; lane owns feature pair (2l, 2l+1). A fp32 (exact residual).
__global__ __launch_bounds__(256) void k_agg(const half2_t* __restrict__ Hh,
                      float* __restrict__ A,
                      const int* __restrict__ rowptr, const int* __restrict__ csrc,
                      const float* __restrict__ dinv,
                      const float* __restrict__ bias, const float* __restrict__ gamma,
                      const float* __restrict__ beta, int res) {
  int lane = threadIdx.x & 63;
  int v = blockIdx.x * 4 + (threadIdx.x >> 6);
  if (v >= NN) return;
  int s0 = rowptr[v], s1 = rowptr[v + 1];
  half2_t hs = Hh[(size_t)v * 64 + lane];          // self-loop term
  float a0 = (float)hs[0], a1 = (float)hs[1];
  int i = s0;
  int head = (s0 + 3) & ~3;
  if (head > s1) head = s1;
  for (; i < head; ++i) {
    half2_t h = Hh[(size_t)csrc[i] * 64 + lane];
    a0 += (float)h[0]; a1 += (float)h[1];
  }
  for (; i + 4 <= s1; i += 4) {                    // 4 gathers in flight
    int4 s4 = *(const int4*)&csrc[i];
    half2_t h0 = Hh[(size_t)s4.x * 64 + lane];
    half2_t h1 = Hh[(size_t)s4.y * 64 + lane];
    half2_t h2 = Hh[(size_t)s4.z * 64 + lane];
    half2_t h3 = Hh[(size_t)s4.w * 64 + lane];
    a0 += (float)h0[0] + (float)h1[0] + (float)h2[0] + (float)h3[0];
    a1 += (float)h0[1] + (float)h1[1] + (float)h2[1] + (float)h3[1];
  }
  for (; i < s1; ++i) {
    half2_t h = Hh[(size_t)csrc[i] * 64 + lane];
    a0 += (float)h[0]; a1 += (float)h[1];
  }
  float dv = dinv[v];
  float2 b2 = *(const float2*)&bias[2 * lane];
  float f0 = a0 * dv + b2.x;
  float f1 = a1 * dv + b2.y;
  float s = f0 + f1, ss = f0 * f0 + f1 * f1;
  #pragma unroll
  for (int o = 1; o < 64; o <<= 1) { s += __shfl_xor(s, o); ss += __shfl_xor(ss, o); }
  float mu = s * (1.f / 128.f);
  float var = ss * (1.f / 128.f) - mu * mu;
  float rs = rsqrtf(var + 1e-5f);
  float2 g2 = *(const float2*)&gamma[2 * lane];
  float2 e2 = *(const float2*)&beta[2 * lane];
  float y0 = fmaxf((f0 - mu) * rs * g2.x + e2.x, 0.f);
  float y1 = fmaxf((f1 - mu) * rs * g2.y + e2.y, 0.f);
  float* Ap = &A[(size_t)v * DIM + 2 * lane];
  if (res) { float2 o2 = *(const float2*)Ap; y0 += o2.x; y1 += o2.y; }
  *(float2*)Ap = make_float2(y0, y1);
}

// ---------------- Global mean pool (batch is sorted, A fp32) ----------------
__global__ __launch_bounds__(128) void k_pool(const float* __restrict__ A,
                                              const int* __restrict__ batch,
                                              float* __restrict__ sums) {
  const int CH = 64;
  int b0 = blockIdx.x * CH;
  int t = threadIdx.x;  // 128
  int nmax = NN - b0; if (nmax > CH) nmax = CH;
  __shared__ int bb[CH];
  if (t < CH) bb[t] = (b0 + t < NN) ? batch[b0 + t] : -1;
  __syncthreads();
  int gfirst = bb[0], glast = bb[nmax - 1];
  if (gfirst == glast) {
    float a0 = 0.f, a1 = 0.f, a2 = 0.f, a3 = 0.f;
    int i = 0;
    for (; i + 4 <= nmax; i += 4) {
      a0 += A[(size_t)(b0 + i + 0) * DIM + t];
      a1 += A[(size_t)(b0 + i + 1) * DIM + t];
      a2 += A[(size_t)(b0 + i + 2) * DIM + t];
      a3 += A[(size_t)(b0 + i + 3) * DIM + t];
    }
    for (; i < nmax; ++i) a0 += A[(size_t)(b0 + i) * DIM + t];
    atomicAdd(&sums[gfirst * DIM + t], (a0 + a1) + (a2 + a3));
  } else {
    float acc = 0.f;
    int cur = gfirst;
    for (int i = 0; i < nmax; i++) {
      int g = bb[i];
      if (g != cur) { atomicAdd(&sums[cur * DIM + t], acc); acc = 0.f; cur = g; }
      acc += A[(size_t)(b0 + i) * DIM + t];
    }
    atomicAdd(&sums[cur * DIM + t], acc);
  }
}

__global__ void k_cnts(const int* __restrict__ batch, float* __restrict__ cnts) {
  int g = threadIdx.x;  // 128
  int lo = 0, hi = NN;
  while (lo < hi) { int mid = (lo + hi) >> 1; if (batch[mid] < g) lo = mid + 1; else hi = mid; }
  int a = lo;
  lo = 0; hi = NN;
  while (lo < hi) { int mid = (lo + hi) >> 1; if (batch[mid] < g + 1) lo = mid + 1; else hi = mid; }
  cnts[g] = (float)(lo - a);
}

// ---------------- Head ----------------
__global__ void k_head(const float* __restrict__ sums, const float* __restrict__ cnts,
                       const float* __restrict__ W1, const float* __restrict__ b1,
                       const float* __restrict__ W2, const float* __restrict__ b2,
                       float* __restrict__ out) {
  int g = blockIdx.x, t = threadIdx.x;  // 64
  __shared__ float p[128];
  float ic = 1.f / fmaxf(cnts[g], 1.f);
  p[t] = sums[g * DIM + t] * ic;
  p[t + 64] = sums[g * DIM + 64 + t] * ic;
  __syncthreads();
  float z = b1[t];
  #pragma unroll 8
  for (int k = 0; k < 128; k++) z += p[k] * W1[k * FCD + t];
  z = fmaxf(z, 0.f);
  float sv = z * W2[t];
  #pragma unroll
  for (int o = 1; o < 64; o <<= 1) sv += __shfl_xor(sv, o);
  if (t == 0) out[g] = 1.f / (1.f + expf(-(sv + b2[0])));
}

extern "C" void kernel_launch(void* const* d_in, const int* in_sizes, int n_in,
                              void* d_out, int out_size, void* d_ws, size_t ws_size,
                              hipStream_t stream) {
  (void)in_sizes; (void)n_in; (void)out_size; (void)ws_size;
  const float* x     = (const float*)d_in[0];
  const int*   ei    = (const int*)d_in[1];
  const int*   batch = (const int*)d_in[2];
  const float* W_in  = (const float*)d_in[3];
  const float* b_in  = (const float*)d_in[4];
  const float* g_in  = (const float*)d_in[5];
  const float* be_in = (const float*)d_in[6];
  const float* W_mid = (const float*)d_in[7];
  const float* b_mid = (const float*)d_in[8];
  const float* g_mid = (const float*)d_in[9];
  const float* be_mid= (const float*)d_in[10];
  const float* W_out = (const float*)d_in[11];
  const float* b_out = (const float*)d_in[12];
  const float* g_out = (const float*)d_in[13];
  const float* be_out= (const float*)d_in[14];
  const float* W1    = (const float*)d_in[15];
  const float* b1    = (const float*)d_in[16];
  const float* W2    = (const float*)d_in[17];
  const float* b2    = (const float*)d_in[18];
  float* out = (float*)d_out;

  // workspace layout (~118 MB)
  char* p = (char*)d_ws;
  auto alloc = [&](size_t bytes) {
    char* r = p;
    p += (bytes + 255) & ~(size_t)255;
    return r;
  };
  float*  A      = (float*)alloc((size_t)NN * DIM * 4);   // node features (fp32)
  half_t* Xh     = (half_t*)alloc((size_t)NN * DIM * 2);  // input x (fp16)
  half_t* Bh     = (half_t*)alloc((size_t)NN * DIM * 2);  // scaled linear output (fp16)
  float*  dinv   = (float*)alloc((size_t)NN * 4);
  int*    rowptr = (int*)alloc((size_t)(NN + 1) * 4);
  int*    csrc   = (int*)alloc((size_t)NE * 4);
  int*    staged = (int*)alloc((size_t)NCH * ECH * 4);
  int*    offmat = (int*)alloc((size_t)NCH * (NBK + 1) * 4);
  int*    gtot   = (int*)alloc((size_t)(NBK + 1) * 4);
  int*    gbase  = (int*)alloc((size_t)(NBK + 1) * 4);
  float*  sums   = (float*)alloc((size_t)NGRAPH * DIM * 4);
  float*  cnts   = (float*)alloc((size_t)NGRAPH * 4);

  const int* rowp = ei;        // sources
  const int* colp = ei + NE;   // targets

  hipMemsetAsync(gtot, 0, (size_t)(NBK + 1) * 4, stream);
  hipMemsetAsync(sums, 0, (size_t)NGRAPH * DIM * 4, stream);

  k_bucketA<<<NCH, 256, 0, stream>>>(rowp, colp, staged, offmat, gtot);
  k_bsum<<<1, 256, 0, stream>>>(gtot, gbase, rowptr);
  k_csrB<<<NBK, 256, 0, stream>>>(staged, offmat, gbase, rowptr, dinv, csrc);
  k_cvt<<<(NN * DIM / 4 + 255) / 256, 256, 0, stream>>>(x, Xh);

  int gemm_grid = ((NN + 63) / 64) * 2;
  for (int l = 0; l < 8; l++) {
    const float *Wl, *bl, *gl, *bel;
    if (l == 0)      { Wl = W_in;  bl = b_in;  gl = g_in;  bel = be_in;  }
    else if (l == 7) { Wl = W_out; bl = b_out; gl = g_out; bel = be_out; }
    else             { Wl = W_mid; bl = b_mid; gl = g_mid; bel = be_mid; }
    const void* in = (l == 0) ? (const void*)Xh : (const void*)A;
    int isHalf = (l == 0) ? 1 : 0;
    k_gemm<<<gemm_grid, 256, 0, stream>>>(in, isHalf, Wl, dinv, Bh);
    int res = (l >= 2 && l <= 6 && (l % 2 == 0)) ? 1 : 0;
    k_agg<<<(NN + 3) / 4, 256, 0, stream>>>((const half2_t*)Bh, A, rowptr, csrc, dinv,
                                            bl, gl, bel, res);
  }

  k_pool<<<(NN + 63) / 64, 128, 0, stream>>>(A, batch, sums);
  k_cnts<<<1, 128, 0, stream>>>(batch, cnts);
  k_head<<<NGRAPH, 64, 0, stream>>>(sums, cnts, W1, b1, W2, b2, out);
}